// Round 7
// baseline (3489.209 us; speedup 1.0000x reference)
//
#include <hip/hip_runtime.h>
#include <hip/hip_bf16.h>

typedef __attribute__((ext_vector_type(8))) __bf16 bf16x8;
typedef __attribute__((ext_vector_type(16))) float f32x16;

#define NB 256     // batch
#define HD 1024    // hidden
#define G3 3072    // 3*H
#define NT 128     // time steps

// ---------------- workspace layout (bytes) ----------------
static const size_t OFF_WHH  = 0;                                   // [d][3072][1024] bf16 (NATURAL)
static const size_t OFF_WIH  = OFF_WHH + (size_t)2*G3*HD*2;         // [d][3072][1024] bf16 (natural)
static const size_t OFF_X16  = OFF_WIH + (size_t)2*G3*HD*2;         // [256][1024] bf16 (natural)
static const size_t OFF_CTR  = OFF_X16 + (size_t)NB*HD*2;           // 2 x u32 barrier counters
static const size_t OFF_H16  = OFF_CTR + 256;                       // [p][d][256][1024] bf16 (natural)
static const size_t OFF_PART = OFF_H16 + (size_t)4*NB*HD*2;         // [b][t][64] f32
// total ~36.2 MB

// NOTE: no k-permutation anywhere. Both MFMA operands are stored natural and
// read with identical chunk patterns, so slot->logical-k maps match (identity)
// regardless of the hardware fragment layout. (Round 6's bug: weights sw23'd,
// h16 natural -> recurrent GEMM paired h[k] with W[sw23(k)].)

// ---------------- prep: cast to bf16, zero h16 parity 0, zero barrier ctrs ----------------
__global__ __launch_bounds__(256) void prep_kernel(
    const float* __restrict__ x,    const float* __restrict__ wihf,
    const float* __restrict__ whhf, const float* __restrict__ wihb,
    const float* __restrict__ whhb, char* __restrict__ ws)
{
  size_t i = (size_t)blockIdx.x*256 + threadIdx.x;   // grid covers 3145728
  __hip_bfloat16* whh = (__hip_bfloat16*)(ws+OFF_WHH);
  __hip_bfloat16* wih = (__hip_bfloat16*)(ws+OFF_WIH);
  __hip_bfloat16* x16 = (__hip_bfloat16*)(ws+OFF_X16);
  __hip_bfloat16* h16 = (__hip_bfloat16*)(ws+OFF_H16);
  if (blockIdx.x==0 && threadIdx.x<2) ((unsigned*)(ws+OFF_CTR))[threadIdx.x] = 0u;
  if (i < (size_t)G3*HD) {
    whh[i]                 = __float2bfloat16(whhf[i]);
    whh[(size_t)G3*HD + i] = __float2bfloat16(whhb[i]);
    wih[i]                 = __float2bfloat16(wihf[i]);
    wih[(size_t)G3*HD + i] = __float2bfloat16(wihb[i]);
  }
  if (i < (size_t)NB*HD)   x16[i] = __float2bfloat16(x[i]);
  if (i < (size_t)2*NB*HD) h16[i]  = __float2bfloat16(0.f);   // parity-0 plane, both dirs
}

// ---------------- persistent bidirectional GRU ----------------
// 256 blocks (1/CU, pinned by 102KB LDS), 256 threads = 4 waves (K-slices of 256).
// bid&7 = (d<<2)|rt  -> all 32 jt-blocks of one (d,rt) share an XCD (bid%8 round-robin),
// so each h-panel is produced AND consumed on one XCD (L2-local).  jt = bid>>3.
// W_hh fragments live in VGPRs (48 x bf16x8) for all 128 steps; gi/h/biases in regs.
// Per step: h16 exchange via parity double-buffer + per-direction counter barrier
// with __threadfence() release/acquire (agent scope -> L2 wb/inv).
__global__ __launch_bounds__(256,1)
void gru_persist(char* __restrict__ ws,
                 const float* __restrict__ bihf, const float* __restrict__ bhhf,
                 const float* __restrict__ bihb, const float* __restrict__ bhhb,
                 const float* __restrict__ wout)
{
  const int bid = blockIdx.x;
  const int xc  = bid & 7;
  const int d   = xc >> 2;           // direction
  const int rt  = xc & 3;            // row tile (64 rows)
  const int jt  = bid >> 3;          // hcol tile (32 cols)
  const int tid = threadIdx.x;
  const int q   = tid >> 6;          // K-slice 0..3 (256 each)
  const int l   = tid & 63;
  const int lrow = l & 31;           // fragment row/col lane component
  const int lh   = l >> 5;           // lane half
  const int erow = l & 15;           // epilogue row within wave's quarter
  const int ec   = l >> 4;           // epilogue col chunk 0..3
  const int r0 = rt*64, j0 = jt*32;

  const __hip_bfloat16* Wih = (const __hip_bfloat16*)(ws+OFF_WIH) + (size_t)d*G3*HD;
  const __hip_bfloat16* Whh = (const __hip_bfloat16*)(ws+OFF_WHH) + (size_t)d*G3*HD;
  const __hip_bfloat16* X16 = (const __hip_bfloat16*)(ws+OFF_X16);
  __hip_bfloat16* H16 = (__hip_bfloat16*)(ws+OFF_H16);        // [p][d][NB][HD]
  unsigned* ctr = (unsigned*)(ws+OFF_CTR);
  float* part = (float*)(ws+OFF_PART);

  __shared__ float red[4][64][100];   // K-slice partials, padded (102.4 KB)

  // per-lane element offset of the wave's K-slice chunks: chunk = q*32 + 2*ks + lh
  const int kbase = (q*32 + lh)*8;

  bf16x8 B[3][16];                    // resident weight fragments (192 VGPR)
  auto loadB = [&](const __hip_bfloat16* Wsrc){
    #pragma unroll
    for (int g=0; g<3; ++g){
      const __hip_bfloat16* p0 = Wsrc + (size_t)(g*1024 + j0 + lrow)*HD + kbase;
      #pragma unroll
      for (int ks=0; ks<16; ++ks) B[g][ks] = *(const bf16x8*)(p0 + ks*16);
    }
  };

  f32x16 acc[2][3];
  auto gemm = [&](const __hip_bfloat16* Asrc){
    #pragma unroll
    for (int mi=0;mi<2;++mi)
      #pragma unroll
      for (int g=0;g<3;++g)
        #pragma unroll
        for (int e=0;e<16;++e) acc[mi][g][e] = 0.f;
    const __hip_bfloat16* pa0 = Asrc + (size_t)(r0 + lrow)*HD + kbase;
    const __hip_bfloat16* pa1 = pa0 + 32*HD;
    #pragma unroll
    for (int bt=0; bt<4; ++bt){
      bf16x8 a0[4], a1[4];
      #pragma unroll
      for (int ks=0; ks<4; ++ks){
        a0[ks] = *(const bf16x8*)(pa0 + (bt*4+ks)*16);
        a1[ks] = *(const bf16x8*)(pa1 + (bt*4+ks)*16);
      }
      #pragma unroll
      for (int ks=0; ks<4; ++ks)
        #pragma unroll
        for (int g=0; g<3; ++g){
          acc[0][g] = __builtin_amdgcn_mfma_f32_32x32x16_bf16(a0[ks], B[g][bt*4+ks], acc[0][g],0,0,0);
          acc[1][g] = __builtin_amdgcn_mfma_f32_32x32x16_bf16(a1[ks], B[g][bt*4+ks], acc[1][g],0,0,0);
        }
    }
  };

  float val[3][8];
  auto reduce = [&](){
    #pragma unroll
    for (int mi=0;mi<2;++mi)
      #pragma unroll
      for (int g=0;g<3;++g)
        #pragma unroll
        for (int e=0;e<16;++e){
          int rl = mi*32 + (e&3) + 8*(e>>2) + 4*lh;   // validated C/D row map
          red[q][rl][g*32 + lrow] = acc[mi][g][e];
        }
    __syncthreads();
    #pragma unroll
    for (int g=0; g<3; ++g){
      #pragma unroll
      for (int c=0;c<8;++c) val[g][c] = 0.f;
      #pragma unroll
      for (int qq=0; qq<4; ++qq){
        const float* base = &red[qq][q*16+erow][g*32 + ec*8];
        float4 v0 = *(const float4*)base;
        float4 v1 = *(const float4*)(base+4);
        val[g][0]+=v0.x; val[g][1]+=v0.y; val[g][2]+=v0.z; val[g][3]+=v0.w;
        val[g][4]+=v1.x; val[g][5]+=v1.y; val[g][6]+=v1.z; val[g][7]+=v1.w;
      }
    }
    __syncthreads();
  };

  // ---- step -1: gi = x @ W_ih^T (+ biases folded), kept in registers ----
  loadB(Wih);
  gemm(X16);
  reduce();
  const float* bih = d ? bihb : bihf;
  const float* bhh = d ? bhhb : bhhf;
  const int cg = j0 + ec*8;           // lane's 8-col chunk within gate
  float gir[8], giz[8], gin[8], bhn[8], wo8[8], h[8];
  #pragma unroll
  for (int c=0;c<8;++c){
    gir[c] = val[0][c] + bih[cg+c]      + bhh[cg+c];
    giz[c] = val[1][c] + bih[1024+cg+c] + bhh[1024+cg+c];
    gin[c] = val[2][c] + bih[2048+cg+c];
    bhn[c] = bhh[2048+cg+c];
    wo8[c] = wout[d*HD + cg + c];
    h[c]   = 0.f;
  }

  loadB(Whh);                          // recurrent weights resident from here on
  const int myrow = r0 + q*16 + erow;  // global batch row this lane owns
  const size_t hplane = (size_t)2*NB*HD;

  for (int t=0; t<NT; ++t){
    const __hip_bfloat16* hs = H16 + (size_t)(t&1)*hplane + (size_t)d*NB*HD;
    gemm(hs);
    reduce();
    bf16x8 hv;
    float pp = 0.f;
    #pragma unroll
    for (int c=0;c<8;++c){
      float rr = 1.f/(1.f+__expf(-(gir[c]+val[0][c])));
      float zz = 1.f/(1.f+__expf(-(giz[c]+val[1][c])));
      float ng = tanhf(gin[c] + rr*(val[2][c]+bhn[c]));
      h[c] = (1.f-zz)*ng + zz*h[c];
      hv[c] = (__bf16)h[c];
      pp += h[c]*wo8[c];
    }
    __hip_bfloat16* hd = H16 + (size_t)((t+1)&1)*hplane + (size_t)d*NB*HD;
    *(bf16x8*)(hd + (size_t)myrow*HD + cg) = hv;
    pp += __shfl_xor(pp, 16, 64);
    pp += __shfl_xor(pp, 32, 64);
    if (l < 16) part[((size_t)myrow*NT + t)*64 + d*32 + jt] = pp;

    if (t < NT-1){
      __syncthreads();                 // all reads of h_t and writes of h_{t+1} complete (to L2)
      if (tid == 0){
        __threadfence();               // release: wb L2 -> h_{t+1} visible device-wide
        atomicAdd(&ctr[d], 1u);
        const unsigned tgt = 128u*(unsigned)(t+1);
        while (__hip_atomic_load(&ctr[d], __ATOMIC_RELAXED, __HIP_MEMORY_SCOPE_AGENT) < tgt)
          __builtin_amdgcn_s_sleep(2);
        __threadfence();               // acquire: inv L1/L2 -> fresh h_{t+1} reads
      }
      __syncthreads();
    }
  }
}

// ---------------- finalize: one wave per (b,t) output, f32 OUTPUT ----------------
__global__ __launch_bounds__(256) void finalize_kernel(
    const char* __restrict__ ws, const float* __restrict__ bout,
    float* __restrict__ out)
{
  int widx = blockIdx.x*4 + (threadIdx.x>>6);   // output index b*128+t, 32768 total
  int lane = threadIdx.x & 63;
  const float* part = (const float*)(ws+OFF_PART);
  float v = part[(size_t)widx*64 + lane];
  #pragma unroll
  for (int m=1;m<64;m<<=1) v += __shfl_xor(v, m, 64);
  if (lane==0) out[widx] = v + bout[0];
}

// ---------------- launch ----------------
extern "C" void kernel_launch(void* const* d_in, const int* in_sizes, int n_in,
                              void* d_out, int out_size, void* d_ws, size_t ws_size,
                              hipStream_t stream)
{
  const float* x    = (const float*)d_in[0];
  // d_in[1] = n (always 128 for this problem)
  const float* wihf = (const float*)d_in[2];
  const float* whhf = (const float*)d_in[3];
  const float* bihf = (const float*)d_in[4];
  const float* bhhf = (const float*)d_in[5];
  const float* wihb = (const float*)d_in[6];
  const float* whhb = (const float*)d_in[7];
  const float* bihb = (const float*)d_in[8];
  const float* bhhb = (const float*)d_in[9];
  const float* wout = (const float*)d_in[10];
  const float* bout = (const float*)d_in[11];
  char* ws = (char*)d_ws;
  float* out = (float*)d_out;

  prep_kernel<<<12288, 256, 0, stream>>>(x, wihf, whhf, wihb, whhb, ws);
  gru_persist<<<256, 256, 0, stream>>>(ws, bihf, bhhf, bihb, bhhb, wout);
  finalize_kernel<<<8192, 256, 0, stream>>>(ws, bout, out);
}

// Round 9
// 1193.037 us; speedup vs baseline: 2.9246x; 2.9246x over previous
//
#include <hip/hip_runtime.h>
#include <hip/hip_bf16.h>

typedef __attribute__((ext_vector_type(8))) __bf16 bf16x8;
typedef __attribute__((ext_vector_type(16))) float f32x16;
typedef __attribute__((ext_vector_type(4)))  float f32x4;

#define NB 256     // batch
#define HD 1024    // hidden
#define G3 3072    // 3*H
#define NT 128     // time steps

// ---------------- workspace layout (bytes) ----------------
static const size_t OFF_WHH  = 0;                                   // [d][3072][1024] bf16 (natural)
static const size_t OFF_WIH  = OFF_WHH + (size_t)2*G3*HD*2;         // [d][3072][1024] bf16 (natural)
static const size_t OFF_X16  = OFF_WIH + (size_t)2*G3*HD*2;         // [256][1024] bf16 (natural)
static const size_t OFF_CTR  = OFF_X16 + (size_t)NB*HD*2;           // 8 group counters, 128B apart (1KB)
static const size_t OFF_H16  = OFF_CTR + 1024;                      // [p][d][256][1024] bf16 (natural)
static const size_t OFF_PART = OFF_H16 + (size_t)4*NB*HD*2;         // [b][t][64] f32
// total ~36.2 MB

// ---------------- prep: cast to bf16, zero h16 parity 0, zero barrier ctrs ----------------
__global__ __launch_bounds__(256) void prep_kernel(
    const float* __restrict__ x,    const float* __restrict__ wihf,
    const float* __restrict__ whhf, const float* __restrict__ wihb,
    const float* __restrict__ whhb, char* __restrict__ ws)
{
  size_t i = (size_t)blockIdx.x*256 + threadIdx.x;   // grid covers 3145728
  __hip_bfloat16* whh = (__hip_bfloat16*)(ws+OFF_WHH);
  __hip_bfloat16* wih = (__hip_bfloat16*)(ws+OFF_WIH);
  __hip_bfloat16* x16 = (__hip_bfloat16*)(ws+OFF_X16);
  __hip_bfloat16* h16 = (__hip_bfloat16*)(ws+OFF_H16);
  if (blockIdx.x==0 && threadIdx.x<256) ((unsigned*)(ws+OFF_CTR))[threadIdx.x] = 0u;
  if (i < (size_t)G3*HD) {
    whh[i]                 = __float2bfloat16(whhf[i]);
    whh[(size_t)G3*HD + i] = __float2bfloat16(whhb[i]);
    wih[i]                 = __float2bfloat16(wihf[i]);
    wih[(size_t)G3*HD + i] = __float2bfloat16(wihb[i]);
  }
  if (i < (size_t)NB*HD)   x16[i] = __float2bfloat16(x[i]);
  if (i < (size_t)2*NB*HD) h16[i]  = __float2bfloat16(0.f);   // parity-0 plane, both dirs
}

// ---------------- coherent-bypass (sc0 sc1) load/store helpers ----------------
// sc0=bypass L1, sc1=bypass L2 -> reads/writes go to the device coherence point
// (L3). This removes the need for buffer_wbl2/buffer_inv fences entirely.
// NOTE: must use ext_vector_type operands (HIP float4 is a struct -> "indirect
// register inputs" asm error).
__device__ inline f32x4 gload_cc(const void* p){
  f32x4 r;
  asm volatile("global_load_dwordx4 %0, %1, off sc0 sc1" : "=v"(r) : "v"(p) : "memory");
  return r;
}
__device__ inline void gstore_cc(void* p, f32x4 v){
  asm volatile("global_store_dwordx4 %0, %1, off sc0 sc1" :: "v"(p), "v"(v) : "memory");
}

// ---------------- persistent bidirectional GRU ----------------
// 256 blocks (1/CU, pinned by 102KB LDS), 256 threads = 4 waves (K-slices of 256).
// bid&7 = (d<<2)|rt = sync group: block (d,rt,jt) consumes h rows produced only
// by blocks (d,rt,*) -> 8 independent 32-block barriers (one ctr each, 128B apart).
// W_hh fragments live in VGPRs (48 x bf16x8) for all 128 steps; gi/h/biases in regs.
// h16 exchange: sc0sc1 stores (write-through) + sc0sc1 loads (bypass stale L1/L2),
// per-wave s_waitcnt vmcnt(0) + device-scope atomicAdd flag. No threadfence.
__global__ __launch_bounds__(256,1)
void gru_persist(char* __restrict__ ws,
                 const float* __restrict__ bihf, const float* __restrict__ bhhf,
                 const float* __restrict__ bihb, const float* __restrict__ bhhb,
                 const float* __restrict__ wout)
{
  const int bid = blockIdx.x;
  const int g8  = bid & 7;           // sync group
  const int d   = g8 >> 2;           // direction
  const int rt  = g8 & 3;            // row tile (64 rows)
  const int jt  = bid >> 3;          // hcol tile (32 cols)
  const int tid = threadIdx.x;
  const int q   = tid >> 6;          // K-slice 0..3 (256 each)
  const int l   = tid & 63;
  const int lrow = l & 31;           // fragment row/col lane component
  const int lh   = l >> 5;           // lane half
  const int erow = l & 15;           // epilogue row within wave's quarter
  const int ec   = l >> 4;           // epilogue col chunk 0..3
  const int r0 = rt*64, j0 = jt*32;

  const __hip_bfloat16* Wih = (const __hip_bfloat16*)(ws+OFF_WIH) + (size_t)d*G3*HD;
  const __hip_bfloat16* Whh = (const __hip_bfloat16*)(ws+OFF_WHH) + (size_t)d*G3*HD;
  const __hip_bfloat16* X16 = (const __hip_bfloat16*)(ws+OFF_X16);
  __hip_bfloat16* H16 = (__hip_bfloat16*)(ws+OFF_H16);        // [p][d][NB][HD]
  unsigned* ctr = (unsigned*)(ws+OFF_CTR);
  float* part = (float*)(ws+OFF_PART);

  __shared__ float red[4][64][100];   // K-slice partials, padded (102.4 KB)

  // per-lane element offset of the wave's K-slice chunks: chunk = q*32 + 2*ks + lh
  const int kbase = (q*32 + lh)*8;

  bf16x8 B[3][16];                    // resident weight fragments (96 VGPR)
  auto loadB = [&](const __hip_bfloat16* Wsrc){
    #pragma unroll
    for (int g=0; g<3; ++g){
      const __hip_bfloat16* p0 = Wsrc + (size_t)(g*1024 + j0 + lrow)*HD + kbase;
      #pragma unroll
      for (int ks=0; ks<16; ++ks) B[g][ks] = *(const bf16x8*)(p0 + ks*16);
    }
  };

  f32x16 acc[2][3];
  // GEMM with coherent-bypass A loads, double-buffered by bt-parity,
  // counted vmcnt(8) (sched_barrier(0) after each wait per rule #18).
  auto gemm_cc = [&](const __hip_bfloat16* Asrc){
    #pragma unroll
    for (int mi=0;mi<2;++mi)
      #pragma unroll
      for (int g=0;g<3;++g)
        #pragma unroll
        for (int e=0;e<16;++e) acc[mi][g][e] = 0.f;
    const __hip_bfloat16* pa0 = Asrc + (size_t)(r0 + lrow)*HD + kbase;
    const __hip_bfloat16* pa1 = pa0 + 32*HD;
    f32x4 A0a[4], A0b[4], A1a[4], A1b[4];   // two named buffers (static idx, rule #20)
    #pragma unroll
    for (int ks=0; ks<4; ++ks){ A0a[ks]=gload_cc(pa0+ks*16);      A1a[ks]=gload_cc(pa1+ks*16); }
    #pragma unroll
    for (int ks=0; ks<4; ++ks){ A0b[ks]=gload_cc(pa0+(4+ks)*16);  A1b[ks]=gload_cc(pa1+(4+ks)*16); }

    // bt=0: consume a-buffers, refill with bt=2
    asm volatile("s_waitcnt vmcnt(8)" ::: "memory");
    __builtin_amdgcn_sched_barrier(0);
    #pragma unroll
    for (int ks=0; ks<4; ++ks){
      bf16x8 a0 = __builtin_bit_cast(bf16x8, A0a[ks]);
      bf16x8 a1 = __builtin_bit_cast(bf16x8, A1a[ks]);
      #pragma unroll
      for (int g=0; g<3; ++g){
        acc[0][g] = __builtin_amdgcn_mfma_f32_32x32x16_bf16(a0, B[g][ks], acc[0][g],0,0,0);
        acc[1][g] = __builtin_amdgcn_mfma_f32_32x32x16_bf16(a1, B[g][ks], acc[1][g],0,0,0);
      }
    }
    #pragma unroll
    for (int ks=0; ks<4; ++ks){ A0a[ks]=gload_cc(pa0+(8+ks)*16);  A1a[ks]=gload_cc(pa1+(8+ks)*16); }

    // bt=1: consume b-buffers, refill with bt=3
    asm volatile("s_waitcnt vmcnt(8)" ::: "memory");
    __builtin_amdgcn_sched_barrier(0);
    #pragma unroll
    for (int ks=0; ks<4; ++ks){
      bf16x8 a0 = __builtin_bit_cast(bf16x8, A0b[ks]);
      bf16x8 a1 = __builtin_bit_cast(bf16x8, A1b[ks]);
      #pragma unroll
      for (int g=0; g<3; ++g){
        acc[0][g] = __builtin_amdgcn_mfma_f32_32x32x16_bf16(a0, B[g][4+ks], acc[0][g],0,0,0);
        acc[1][g] = __builtin_amdgcn_mfma_f32_32x32x16_bf16(a1, B[g][4+ks], acc[1][g],0,0,0);
      }
    }
    #pragma unroll
    for (int ks=0; ks<4; ++ks){ A0b[ks]=gload_cc(pa0+(12+ks)*16); A1b[ks]=gload_cc(pa1+(12+ks)*16); }

    // bt=2: consume a-buffers
    asm volatile("s_waitcnt vmcnt(8)" ::: "memory");
    __builtin_amdgcn_sched_barrier(0);
    #pragma unroll
    for (int ks=0; ks<4; ++ks){
      bf16x8 a0 = __builtin_bit_cast(bf16x8, A0a[ks]);
      bf16x8 a1 = __builtin_bit_cast(bf16x8, A1a[ks]);
      #pragma unroll
      for (int g=0; g<3; ++g){
        acc[0][g] = __builtin_amdgcn_mfma_f32_32x32x16_bf16(a0, B[g][8+ks], acc[0][g],0,0,0);
        acc[1][g] = __builtin_amdgcn_mfma_f32_32x32x16_bf16(a1, B[g][8+ks], acc[1][g],0,0,0);
      }
    }

    // bt=3: consume b-buffers
    asm volatile("s_waitcnt vmcnt(0)" ::: "memory");
    __builtin_amdgcn_sched_barrier(0);
    #pragma unroll
    for (int ks=0; ks<4; ++ks){
      bf16x8 a0 = __builtin_bit_cast(bf16x8, A0b[ks]);
      bf16x8 a1 = __builtin_bit_cast(bf16x8, A1b[ks]);
      #pragma unroll
      for (int g=0; g<3; ++g){
        acc[0][g] = __builtin_amdgcn_mfma_f32_32x32x16_bf16(a0, B[g][12+ks], acc[0][g],0,0,0);
        acc[1][g] = __builtin_amdgcn_mfma_f32_32x32x16_bf16(a1, B[g][12+ks], acc[1][g],0,0,0);
      }
    }
  };

  float val[3][8];
  auto reduce = [&](){
    #pragma unroll
    for (int mi=0;mi<2;++mi)
      #pragma unroll
      for (int g=0;g<3;++g)
        #pragma unroll
        for (int e=0;e<16;++e){
          int rl = mi*32 + (e&3) + 8*(e>>2) + 4*lh;   // validated C/D row map
          red[q][rl][g*32 + lrow] = acc[mi][g][e];
        }
    __syncthreads();
    #pragma unroll
    for (int g=0; g<3; ++g){
      #pragma unroll
      for (int c=0;c<8;++c) val[g][c] = 0.f;
      #pragma unroll
      for (int qq=0; qq<4; ++qq){
        const float* base = &red[qq][q*16+erow][g*32 + ec*8];
        float4 v0 = *(const float4*)base;
        float4 v1 = *(const float4*)(base+4);
        val[g][0]+=v0.x; val[g][1]+=v0.y; val[g][2]+=v0.z; val[g][3]+=v0.w;
        val[g][4]+=v1.x; val[g][5]+=v1.y; val[g][6]+=v1.z; val[g][7]+=v1.w;
      }
    }
    __syncthreads();
  };

  // ---- step -1: gi = x @ W_ih^T (+ biases folded), kept in registers ----
  loadB(Wih);
  gemm_cc(X16);
  reduce();
  const float* bih = d ? bihb : bihf;
  const float* bhh = d ? bhhb : bhhf;
  const int cg = j0 + ec*8;           // lane's 8-col chunk within gate
  float gir[8], giz[8], gin[8], bhn[8], wo8[8], h[8];
  #pragma unroll
  for (int c=0;c<8;++c){
    gir[c] = val[0][c] + bih[cg+c]      + bhh[cg+c];
    giz[c] = val[1][c] + bih[1024+cg+c] + bhh[1024+cg+c];
    gin[c] = val[2][c] + bih[2048+cg+c];
    bhn[c] = bhh[2048+cg+c];
    wo8[c] = wout[d*HD + cg + c];
    h[c]   = 0.f;
  }

  loadB(Whh);                          // recurrent weights resident from here on
  const int myrow = r0 + q*16 + erow;  // global batch row this lane owns
  const size_t hplane = (size_t)2*NB*HD;

  for (int t=0; t<NT; ++t){
    const __hip_bfloat16* hs = H16 + (size_t)(t&1)*hplane + (size_t)d*NB*HD;
    gemm_cc(hs);
    reduce();
    bf16x8 hv;
    float pp = 0.f;
    #pragma unroll
    for (int c=0;c<8;++c){
      float rr = 1.f/(1.f+__expf(-(gir[c]+val[0][c])));
      float zz = 1.f/(1.f+__expf(-(giz[c]+val[1][c])));
      float ng = tanhf(gin[c] + rr*(val[2][c]+bhn[c]));
      h[c] = (1.f-zz)*ng + zz*h[c];
      hv[c] = (__bf16)h[c];
      pp += h[c]*wo8[c];
    }
    __hip_bfloat16* hd = H16 + (size_t)((t+1)&1)*hplane + (size_t)d*NB*HD;
    gstore_cc(hd + (size_t)myrow*HD + cg, __builtin_bit_cast(f32x4, hv));
    pp += __shfl_xor(pp, 16, 64);
    pp += __shfl_xor(pp, 32, 64);
    if (l < 16) part[((size_t)myrow*NT + t)*64 + d*32 + jt] = pp;

    if (t < NT-1){
      // release: each wave drains its OWN stores (vmcnt is per-wave), then
      // block barrier, then one device-scope RMW arrival per block.
      asm volatile("s_waitcnt vmcnt(0)" ::: "memory");
      __syncthreads();
      if (tid == 0){
        atomicAdd(&ctr[g8*32], 1u);
        const unsigned tgt = 32u*(unsigned)(t+1);
        while (__hip_atomic_load(&ctr[g8*32], __ATOMIC_RELAXED, __HIP_MEMORY_SCOPE_AGENT) < tgt)
          __builtin_amdgcn_s_sleep(1);
      }
      __syncthreads();
    }
  }
}

// ---------------- finalize: one wave per (b,t) output, f32 OUTPUT ----------------
__global__ __launch_bounds__(256) void finalize_kernel(
    const char* __restrict__ ws, const float* __restrict__ bout,
    float* __restrict__ out)
{
  int widx = blockIdx.x*4 + (threadIdx.x>>6);   // output index b*128+t, 32768 total
  int lane = threadIdx.x & 63;
  const float* part = (const float*)(ws+OFF_PART);
  float v = part[(size_t)widx*64 + lane];
  #pragma unroll
  for (int m=1;m<64;m<<=1) v += __shfl_xor(v, m, 64);
  if (lane==0) out[widx] = v + bout[0];
}

// ---------------- launch ----------------
extern "C" void kernel_launch(void* const* d_in, const int* in_sizes, int n_in,
                              void* d_out, int out_size, void* d_ws, size_t ws_size,
                              hipStream_t stream)
{
  const float* x    = (const float*)d_in[0];
  // d_in[1] = n (always 128 for this problem)
  const float* wihf = (const float*)d_in[2];
  const float* whhf = (const float*)d_in[3];
  const float* bihf = (const float*)d_in[4];
  const float* bhhf = (const float*)d_in[5];
  const float* wihb = (const float*)d_in[6];
  const float* whhb = (const float*)d_in[7];
  const float* bihb = (const float*)d_in[8];
  const float* bhhb = (const float*)d_in[9];
  const float* wout = (const float*)d_in[10];
  const float* bout = (const float*)d_in[11];
  char* ws = (char*)d_ws;
  float* out = (float*)d_out;

  prep_kernel<<<12288, 256, 0, stream>>>(x, wihf, whhf, wihb, whhb, ws);
  gru_persist<<<256, 256, 0, stream>>>(ws, bihf, bhhf, bihb, bhhb, wout);
  finalize_kernel<<<8192, 256, 0, stream>>>(ws, bout, out);
}